// Round 8
// baseline (2739.018 us; speedup 1.0000x reference)
//
#include <hip/hip_runtime.h>

#define T_IN   24
#define NB     8192
#define HD     512
#define T_OUT  12
#define ROWS   32
#define NBLK   (NB / ROWS)   // 256 blocks = 1 per CU (LDS-pad enforced)

typedef float  f32x4  __attribute__((ext_vector_type(4)));
typedef short  bf16x8 __attribute__((ext_vector_type(8)));

__device__ __forceinline__ unsigned short f2bf(float f){
  unsigned u = __float_as_uint(f);
  u += 0x7fffu + ((u >> 16) & 1u);          // round-to-nearest-even
  return (unsigned short)(u >> 16);
}
__device__ __forceinline__ float bf2f(unsigned short h){
  return __uint_as_float(((unsigned)h) << 16);
}

// XOR-swizzled f32 index into the [ROWS][512] hidden/h2 LDS tile (bijective per row)
__device__ __forceinline__ int swz(int r, int c){
  int ch  = c >> 3;
  int sch = ch ^ (r & 7) ^ ((ch >> 2) & 3);
  return (r << 9) + (sch << 3) + (c & 7);
}

// ---- W_hh -> bf16 hi/lo split, repacked k-chunk-major: [kt][1536][32] ----
__global__ __launch_bounds__(256) void conv_whh(const float* __restrict__ W,
                                                unsigned short* __restrict__ hi,
                                                unsigned short* __restrict__ lo){
  int idx = blockIdx.x * 256 + threadIdx.x;   // 3072 blocks x 256 = 1536*512
  int j = idx >> 9, k = idx & 511;
  float v = W[idx];
  unsigned short h = f2bf(v);
  int o = ((k >> 5) * 1536 + j) * 32 + (k & 31);
  hi[o] = h;
  lo[o] = f2bf(v - bf2f(h));
}

// ---------------- persistent fused decoder ----------------
// Round-8 attn: 4 waves per row, lane owns 2 cols; all 24 E-values held in regs
// (structurally forced residency), 24 INDEPENDENT logit partials (no serial
// online-softmax chain), one tree-reduce + LDS combine + 24-wide softmax, ctx
// from registers. waves_per_eu(4,4) pins the allocator to the real occupancy.
__global__ __launch_bounds__(1024) __attribute__((amdgpu_waves_per_eu(4, 4)))
void decoder(
    const float* __restrict__ enc,       // f32 [t][b][h]
    const float* __restrict__ ehid,      // f32 [b][h]
    const float* __restrict__ last0,     // f32 [b][4]
    const float* __restrict__ pe,        // f32 [12][4]
    const float* __restrict__ W_ih,      // f32 [1536][8]
    const float* __restrict__ b_ih,      // f32 [1536]
    const float* __restrict__ b_hh,      // f32 [1536]
    const float* __restrict__ Wlin,      // f32 [1024]
    const float* __restrict__ blin,      // f32 [1]
    const unsigned short* __restrict__ Whi,  // bf16 [16][1536][32]
    const unsigned short* __restrict__ Wlo,
    float* __restrict__ outp)            // f32 [b][12]
{
  // 64KB live + pad: 2 x ~83KB > 160KB forces exactly 1 block/CU
  __shared__ float hid_s[ROWS * HD + 4352];
  __shared__ float last_s[ROWS][4];
  __shared__ float lp_s[4][4][28];   // [row-in-grp][wave-quarter][24 logit partials]
  __shared__ float wts_s[4][28];     // [row-in-grp][24 softmax weights]
  __shared__ float cd_s[ROWS][4];    // ctx-dot partials per (row, quarter)

  const int tid = threadIdx.x;
  const int l   = tid & 63;
  const int w   = tid >> 6;        // wave 0..15
  // GEMM / epilogue / out-dot mapping (unchanged from round 7)
  const int li  = l & 31;
  const int hf  = l >> 5;
  const int rl  = 2 * w + hf;      // row 0..31 (half-wave per row)
  const int cb  = li * 4;
  const int fi  = l & 15;
  const int fg  = l >> 4;
  // attn mapping: 4 waves per row, lane owns cols {ac, ac+1}
  const int r_in = w >> 2;         // row-in-group 0..3
  const int wq   = w & 3;          // quarter 0..3
  const int ac   = wq * 128 + l * 2;

  // ---- init: hidden <- encoder_hid, last <- last_init ----
  {
    const float* hb = ehid + (size_t)(blockIdx.x * ROWS + rl) * HD + cb;
    #pragma unroll
    for (int q = 0; q < 4; q++)
      *(f32x4*)(hid_s + swz(rl, cb + q * 128)) = *(const f32x4*)(hb + q * 128);
    if (li == 0)
      *(float4*)(&last_s[rl][0]) = *(const float4*)(last0 + (size_t)(blockIdx.x * ROWS + rl) * 4);
  }
  __syncthreads();

  const size_t tstride = (size_t)NB * HD;

  for (int s = 0; s < T_OUT; s++){
    // ========== A. attention: 8 groups x 4 rows, parallel logits ==========
    for (int grp = 0; grp < 8; grp++){
      const int rloc = grp * 4 + r_in;
      const size_t rgg = (size_t)(blockIdx.x * ROWS + rloc);
      const int ho = swz(rloc, ac);
      float2 hh = *(const float2*)(hid_s + ho);
      const float* eb2 = enc + rgg * HD + ac;

      // 24 independent loads (all stay live for ctx) + 24 independent partials
      float2 E[24];
      float  p[24];
      #pragma unroll
      for (int t = 0; t < 24; t++)
        E[t] = *(const float2*)(eb2 + (size_t)t * tstride);
      #pragma unroll
      for (int t = 0; t < 24; t++)
        p[t] = E[t].x * hh.x + E[t].y * hh.y;

      // tree-reduce 24 partials across the wave's 64 lanes (round-3 verified)
      const int b0 = l & 1, b1 = (l >> 1) & 1, b2 = (l >> 2) & 1;
      float q12[12];
      #pragma unroll
      for (int j = 0; j < 12; j++){
        float send = b0 ? p[j] : p[12 + j];
        float keep = b0 ? p[12 + j] : p[j];
        q12[j] = keep + __shfl_xor(send, 1);
      }
      float r6[6];
      #pragma unroll
      for (int j = 0; j < 6; j++){
        float send = b1 ? q12[j] : q12[6 + j];
        float keep = b1 ? q12[6 + j] : q12[j];
        r6[j] = keep + __shfl_xor(send, 2);
      }
      float s3[3];
      #pragma unroll
      for (int j = 0; j < 3; j++){
        float send = b2 ? r6[j] : r6[3 + j];
        float keep = b2 ? r6[3 + j] : r6[j];
        s3[j] = keep + __shfl_xor(send, 4);
      }
      #pragma unroll
      for (int j = 0; j < 3; j++){
        s3[j] += __shfl_xor(s3[j], 8);
        s3[j] += __shfl_xor(s3[j], 16);
        s3[j] += __shfl_xor(s3[j], 32);
      }
      if (l < 8){
        int tb = 12 * b0 + 6 * b1 + 3 * b2;
        lp_s[r_in][wq][tb + 0] = s3[0];
        lp_s[r_in][wq][tb + 1] = s3[1];
        lp_s[r_in][wq][tb + 2] = s3[2];
      }
      __syncthreads();

      // combine quarters + softmax (wave with wq==0; width-32 shuffles)
      if (wq == 0){
        float v = -3.0e38f;
        if (l < 24)
          v = lp_s[r_in][0][l] + lp_s[r_in][1][l] + lp_s[r_in][2][l] + lp_s[r_in][3][l];
        float mx = v;
        #pragma unroll
        for (int o = 16; o; o >>= 1) mx = fmaxf(mx, __shfl_xor(mx, o, 32));
        float ex = (l < 24) ? exp2f((v - mx) * 1.44269504f) : 0.f;
        float sm = ex;
        #pragma unroll
        for (int o = 16; o; o >>= 1) sm += __shfl_xor(sm, o, 32);
        if (l < 24) wts_s[r_in][l] = ex / sm;
      }
      __syncthreads();

      // ctx from registers; h2 = hidden + ctx; ctx part of out-dot
      float cx0 = 0.f, cx1 = 0.f;
      #pragma unroll
      for (int t = 0; t < 24; t++){
        float wt = wts_s[r_in][t];
        cx0 += wt * E[t].x;
        cx1 += wt * E[t].y;
      }
      float2 h2; h2.x = hh.x + cx0; h2.y = hh.y + cx1;
      *(float2*)(hid_s + ho) = h2;
      float cd = cx0 * Wlin[HD + ac] + cx1 * Wlin[HD + ac + 1];
      #pragma unroll
      for (int o = 32; o; o >>= 1) cd += __shfl_xor(cd, o);
      if (l == 0) cd_s[rloc][wq] = cd;
    }
    __syncthreads();   // bar1: all h2 + cd visible

    // ===== C. GEMM k-sweep (gh = h2 @ W_hh^T, split bf16 3-product) =====
    f32x4 acc[3][2][2];   // [gate][jhalf][mtile]
    #pragma unroll
    for (int a = 0; a < 3; a++)
      #pragma unroll
      for (int b = 0; b < 2; b++)
        #pragma unroll
        for (int c = 0; c < 2; c++)
          acc[a][b][c] = (f32x4){0.f, 0.f, 0.f, 0.f};

    #pragma unroll 2
    for (int kt = 0; kt < 16; kt++){
      bf16x8 ah[2], al8[2];
      #pragma unroll
      for (int mt = 0; mt < 2; mt++){
        int o = swz(mt * 16 + fi, kt * 32 + fg * 8);
        f32x4 a0 = *(const f32x4*)(hid_s + o);
        f32x4 a1 = *(const f32x4*)(hid_s + o + 4);
        #pragma unroll
        for (int e = 0; e < 4; e++){
          unsigned short h0 = f2bf(a0[e]);
          unsigned short h1 = f2bf(a1[e]);
          ah[mt][e]      = (short)h0;
          ah[mt][e + 4]  = (short)h1;
          al8[mt][e]     = (short)f2bf(a0[e] - bf2f(h0));
          al8[mt][e + 4] = (short)f2bf(a1[e] - bf2f(h1));
        }
      }
      #pragma unroll
      for (int g = 0; g < 3; g++)
        #pragma unroll
        for (int jh = 0; jh < 2; jh++){
          size_t boff = ((size_t)kt * 1536 + g * 512 + jh * 256 + w * 16 + fi) * 32 + fg * 8;
          bf16x8 bh = *(const bf16x8*)(Whi + boff);
          bf16x8 bl = *(const bf16x8*)(Wlo + boff);
          #pragma unroll
          for (int mt = 0; mt < 2; mt++){
            acc[g][jh][mt] = __builtin_amdgcn_mfma_f32_16x16x32_bf16(ah[mt],  bh, acc[g][jh][mt], 0, 0, 0);
            acc[g][jh][mt] = __builtin_amdgcn_mfma_f32_16x16x32_bf16(al8[mt], bh, acc[g][jh][mt], 0, 0, 0);
            acc[g][jh][mt] = __builtin_amdgcn_mfma_f32_16x16x32_bf16(ah[mt],  bl, acc[g][jh][mt], 0, 0, 0);
          }
        }
    }
    __syncthreads();   // bar2: all h2 reads done before hidden overwrite

    // ================= E. fused GRU epilogue =================
    const float pe0 = pe[s * 4 + 0], pe1 = pe[s * 4 + 1],
                pe2 = pe[s * 4 + 2], pe3 = pe[s * 4 + 3];
    #pragma unroll
    for (int jh = 0; jh < 2; jh++){
      int j = w * 16 + jh * 256 + fi;
      const float* wrp = W_ih + (size_t)j * 8;
      const float* wzp = W_ih + (size_t)(512 + j) * 8;
      const float* wnp = W_ih + (size_t)(1024 + j) * 8;
      float4 wr0 = *(const float4*)wrp, wr1 = *(const float4*)(wrp + 4);
      float4 wz0 = *(const float4*)wzp, wz1 = *(const float4*)(wzp + 4);
      float4 wn0 = *(const float4*)wnp, wn1 = *(const float4*)(wnp + 4);
      float cr = pe0*wr1.x + pe1*wr1.y + pe2*wr1.z + pe3*wr1.w + b_ih[j]        + b_hh[j];
      float cz = pe0*wz1.x + pe1*wz1.y + pe2*wz1.z + pe3*wz1.w + b_ih[512 + j]  + b_hh[512 + j];
      float cn = pe0*wn1.x + pe1*wn1.y + pe2*wn1.z + pe3*wn1.w + b_ih[1024 + j];
      const float bhn = b_hh[1024 + j];
      #pragma unroll
      for (int mt = 0; mt < 2; mt++){
        #pragma unroll
        for (int q = 0; q < 4; q++){
          int row = mt * 16 + fg * 4 + q;       // C-frag row
          float4 x = *(const float4*)(&last_s[row][0]);
          float gr = x.x*wr0.x + x.y*wr0.y + x.z*wr0.z + x.w*wr0.w + cr + acc[0][jh][mt][q];
          float gz = x.x*wz0.x + x.y*wz0.y + x.z*wz0.z + x.w*wz0.w + cz + acc[1][jh][mt][q];
          float gn = x.x*wn0.x + x.y*wn0.y + x.z*wn0.z + x.w*wn0.w + cn;
          float r = 1.f / (1.f + exp2f(-1.44269504f * gr));
          float z = 1.f / (1.f + exp2f(-1.44269504f * gz));
          float nn = gn + r * (acc[2][jh][mt][q] + bhn);
          float th = 1.f - 2.f / (1.f + exp2f(2.88539008f * nn));   // tanh
          int ho2 = swz(row, j);
          float h = hid_s[ho2];                 // h2
          hid_s[ho2] = (1.f - z) * th + z * h;  // hidden'
        }
      }
    }
    __syncthreads();   // bar3: hidden' visible

    // ================= G. output dot + last-ring update =================
    float pdot = 0.f;
    #pragma unroll
    for (int q = 0; q < 4; q++){
      f32x4 hv = *(const f32x4*)(hid_s + swz(rl, cb + q * 128));
      f32x4 wv = *(const f32x4*)(Wlin + cb + q * 128);
      #pragma unroll
      for (int e = 0; e < 4; e++) pdot += hv[e] * wv[e];
    }
    pdot += __shfl_xor(pdot, 1); pdot += __shfl_xor(pdot, 2);
    pdot += __shfl_xor(pdot, 4); pdot += __shfl_xor(pdot, 8);
    pdot += __shfl_xor(pdot, 16);
    if (li == 0){
      float val = pdot + cd_s[rl][0] + cd_s[rl][1] + cd_s[rl][2] + cd_s[rl][3] + blin[0];
      outp[(size_t)(blockIdx.x * ROWS + rl) * T_OUT + s] = val;
      float4 old = *(float4*)(&last_s[rl][0]);
      last_s[rl][0] = val;   last_s[rl][1] = old.x;
      last_s[rl][2] = old.y; last_s[rl][3] = old.z;
    }
    // no extra barrier: next step's first group-write is behind two barriers,
    // and all hid_s/last_s touches here are owner-only (round-4/5 analysis).
  }
}

extern "C" void kernel_launch(void* const* d_in, const int* in_sizes, int n_in,
                              void* d_out, int out_size, void* d_ws, size_t ws_size,
                              hipStream_t stream){
  (void)in_sizes; (void)n_in; (void)out_size; (void)ws_size;
  const float* enc   = (const float*)d_in[0];
  const float* ehid  = (const float*)d_in[1];
  const float* last0 = (const float*)d_in[2];
  const float* pe    = (const float*)d_in[3];
  const float* W_ih  = (const float*)d_in[4];
  const float* W_hh  = (const float*)d_in[5];
  const float* b_ih  = (const float*)d_in[6];
  const float* b_hh  = (const float*)d_in[7];
  const float* W_lin = (const float*)d_in[8];
  const float* b_lin = (const float*)d_in[9];
  float* outp = (float*)d_out;

  char* ws = (char*)d_ws;
  unsigned short* whh_hi = (unsigned short*)ws;
  unsigned short* whh_lo = whh_hi + (size_t)1536 * 512;

  conv_whh<<<3072, 256, 0, stream>>>(W_hh, whh_hi, whh_lo);
  decoder<<<NBLK, 1024, 0, stream>>>(enc, ehid, last0, pe, W_ih, b_ih, b_hh,
                                     W_lin, b_lin, whh_hi, whh_lo, outp);
}

// Round 9
// 1438.542 us; speedup vs baseline: 1.9040x; 1.9040x over previous
//
#include <hip/hip_runtime.h>

#define T_IN   24
#define NB     8192
#define HD     512
#define T_OUT  12

typedef float  f32x4  __attribute__((ext_vector_type(4)));
typedef short  bf16x8 __attribute__((ext_vector_type(8)));

// async global->LDS, 16B per lane; LDS dest must be wave-uniform base + lane*16
#define GLD16(g, l) __builtin_amdgcn_global_load_lds( \
    (__attribute__((address_space(1))) void*)(g), \
    (__attribute__((address_space(3))) void*)(l), 16, 0, 0)

__device__ __forceinline__ unsigned short f2bf(float f){
  unsigned u = __float_as_uint(f);
  u += 0x7fffu + ((u >> 16) & 1u);          // round-to-nearest-even
  return (unsigned short)(u >> 16);
}
__device__ __forceinline__ float bf2f(unsigned short h){
  return __uint_as_float(((unsigned)h) << 16);
}
__device__ __forceinline__ float wsum(float v){
  #pragma unroll
  for (int o = 32; o; o >>= 1) v += __shfl_xor(v, o);
  return v;
}

// ---------------- W_hh -> bf16 hi/lo split (once per call) ----------------
__global__ __launch_bounds__(256) void conv_whh(const float* __restrict__ W,
                                                unsigned short* __restrict__ hi,
                                                unsigned short* __restrict__ lo){
  int i = blockIdx.x * 256 + threadIdx.x;
  float v = W[i];
  unsigned short h = f2bf(v);
  hi[i] = h;
  lo[i] = f2bf(v - bf2f(h));
}

// ------- fused: prev-step out finalize + attention + h2 (bf16 hi/lo) -------
// One block per batch row. Thread owns enc columns {2tid, 2tid+1} in registers;
// f32 logits throughout (precision-critical — round-2 failure).
// rev=1 walks the batch in REVERSE so alternate steps start on the rows the
// previous pass read last -> Infinity-Cache (256MB vs 403MB enc) retention.
__global__ __launch_bounds__(256, 4) void attn_step(
    const float* __restrict__ enc,       // f32 [t][b][h]
    const float* __restrict__ hid_in,    // f32 [b][h]
    const float* __restrict__ Wlin,
    const float* __restrict__ blin,
    const float* __restrict__ last_init,
    float* __restrict__ last_ws,
    float* __restrict__ ctxdot,
    unsigned short* __restrict__ h2hi,
    unsigned short* __restrict__ h2lo,
    float* __restrict__ outp,
    int step, int rev)
{
  __shared__ float lpart[4][28];   // per-wave logit partials (24 used)
  __shared__ float po_s[4];        // per-wave prev-output partials
  __shared__ float red2[4];        // per-wave ctx-output partials
  __shared__ float wts_s[T_IN];    // softmax weights

  const int b   = rev ? (NB - 1 - (int)blockIdx.x) : (int)blockIdx.x;
  const int tid = threadIdx.x;
  const int l   = tid & 63;
  const int w   = tid >> 6;
  const int c0  = 2 * tid;         // owned columns: c0, c0+1

  // --- load enc columns (24 x float2) + hidden + Wlin slices into registers ---
  float2 e[T_IN];
  #pragma unroll
  for (int t = 0; t < T_IN; t++)
    e[t] = *(const float2*)(enc + ((size_t)t * NB + b) * HD + c0);
  float2 hh  = *(const float2*)(hid_in + (size_t)b * HD + c0);
  float2 wl0 = *(const float2*)(Wlin + c0);        // hidden part
  float2 wl1 = *(const float2*)(Wlin + HD + c0);   // context part

  // --- per-thread logit partials ---
  float p[T_IN];
  #pragma unroll
  for (int t = 0; t < T_IN; t++) p[t] = e[t].x * hh.x + e[t].y * hh.y;

  // prev-step output partial (dot(hidden, Wlin[0:512]))
  float po = hh.x * wl0.x + hh.y * wl0.y;
  po = wsum(po);
  if (l == 0) po_s[w] = po;

  // --- tree-reduce 24 partials across 64 lanes (halving + butterfly) ---
  const int b0 = l & 1, b1 = (l >> 1) & 1, b2 = (l >> 2) & 1;
  float q[12];
  #pragma unroll
  for (int j = 0; j < 12; j++){
    float send = b0 ? p[j] : p[12 + j];
    float keep = b0 ? p[12 + j] : p[j];
    q[j] = keep + __shfl_xor(send, 1);
  }
  float r6[6];
  #pragma unroll
  for (int j = 0; j < 6; j++){
    float send = b1 ? q[j] : q[6 + j];
    float keep = b1 ? q[6 + j] : q[j];
    r6[j] = keep + __shfl_xor(send, 2);
  }
  float s3[3];
  #pragma unroll
  for (int j = 0; j < 3; j++){
    float send = b2 ? r6[j] : r6[3 + j];
    float keep = b2 ? r6[3 + j] : r6[j];
    s3[j] = keep + __shfl_xor(send, 4);
  }
  #pragma unroll
  for (int j = 0; j < 3; j++){
    s3[j] += __shfl_xor(s3[j], 8);
    s3[j] += __shfl_xor(s3[j], 16);
    s3[j] += __shfl_xor(s3[j], 32);
  }
  if (l < 8){
    int tb = 12 * b0 + 6 * b1 + 3 * b2;    // lane's t-base
    lpart[w][tb + 0] = s3[0];
    lpart[w][tb + 1] = s3[1];
    lpart[w][tb + 2] = s3[2];
  }
  __syncthreads();

  // --- wave 0: softmax over 24 logits ---
  if (w == 0){
    float v = -3.0e38f;
    if (l < T_IN) v = lpart[0][l] + lpart[1][l] + lpart[2][l] + lpart[3][l];
    float m = v;
    #pragma unroll
    for (int o = 32; o; o >>= 1) m = fmaxf(m, __shfl_xor(m, o));
    float ex = (l < T_IN) ? exp2f((v - m) * 1.44269504f) : 0.f;
    float s = wsum(ex);
    if (l < T_IN) wts_s[l] = ex / s;
  }
  // --- wave 1 lane 0: finalize prev output + shift `last` ---
  if (w == 1 && l == 0){
    if (step > 0){
      float val = po_s[0] + po_s[1] + po_s[2] + po_s[3] + ctxdot[b];
      outp[(size_t)b * T_OUT + (step - 1)] = val;
      float4 old = *(const float4*)(last_ws + (size_t)b * 4);
      float4 nl; nl.x = val; nl.y = old.x; nl.z = old.y; nl.w = old.z;
      *(float4*)(last_ws + (size_t)b * 4) = nl;
    } else {
      *(float4*)(last_ws + (size_t)b * 4) = *(const float4*)(last_init + (size_t)b * 4);
    }
  }
  __syncthreads();

  // --- context from registers (f32) ---
  float c0v = 0.f, c1v = 0.f;
  #pragma unroll
  for (int t = 0; t < T_IN; t++){
    float wt = wts_s[t];
    c0v += wt * e[t].x;
    c1v += wt * e[t].y;
  }
  float h20 = hh.x + c0v;
  float h21 = hh.y + c1v;
  size_t base = (size_t)b * HD + c0;
  unsigned short q0 = f2bf(h20), q1 = f2bf(h21);
  *(unsigned int*)(h2hi + base) = (unsigned)q0 | ((unsigned)q1 << 16);
  unsigned short r0 = f2bf(h20 - bf2f(q0)), r1 = f2bf(h21 - bf2f(q1));
  *(unsigned int*)(h2lo + base) = (unsigned)r0 | ((unsigned)r1 << 16);

  // context part of the output dot (+ bias), consumed next step
  float pc = c0v * wl1.x + c1v * wl1.y;
  pc = wsum(pc);
  if (l == 0) red2[w] = pc;
  __syncthreads();
  if (tid == 0) ctxdot[b] = red2[0] + red2[1] + red2[2] + red2[3] + blin[0];
}

// ------- split-bf16 MFMA GEMM (gh = h2 @ W_hh^T, 3 gates) + fused GRU gates -------
// Flat 512-block grid with XCD-aware remap: the 8 N-panel blocks sharing an
// A-tile all land on XCD (x>>3) -> A-tile read once per XCD, B stays L2-warm.
__global__ __launch_bounds__(512, 4) void gru_gemm(
    const unsigned short* __restrict__ Ahi,
    const unsigned short* __restrict__ Alo,
    const unsigned short* __restrict__ Bhi,
    const unsigned short* __restrict__ Blo,
    const float* __restrict__ last_ws,
    const float* __restrict__ pe,
    const float* __restrict__ W_ih,
    const float* __restrict__ b_ih,
    const float* __restrict__ b_hh,
    float* __restrict__ hidden,
    int step)
{
  __shared__ __align__(16) unsigned short smem[2 * 20480];   // 80 KB double-buffered
  const int tid = threadIdx.x;
  const int bid = blockIdx.x;
  const int xk  = bid & 7;                 // XCD (dispatch round-robin heuristic)
  const int sl  = bid >> 3;
  const int xt  = (xk << 3) | (sl >> 3);   // M-tile 0..63
  const int yt  = sl & 7;                  // N-tile 0..7
  const int b0  = xt * 128;
  const int n0  = yt * 64;
  const int l   = tid & 63;
  const int wv  = tid >> 6;
  const int wm  = wv >> 2;
  const int wn  = wv & 3;
  const int lr  = l & 15;
  const int lkb = (l >> 4) << 4;

  f32x4 acc[3][4];
  #pragma unroll
  for (int g = 0; g < 3; g++)
    #pragma unroll
    for (int mi = 0; mi < 4; mi++)
      acc[g][mi] = (f32x4){0.f, 0.f, 0.f, 0.f};

  auto stage = [&](int kt, int buf){
    unsigned short* sb = smem + buf * 20480;
    {
      int row = tid >> 2;
      int pb  = (tid & 3) << 4;
      int ke  = (pb ^ ((row & 3) << 4)) >> 1;
      size_t ga = (size_t)(b0 + row) * HD + kt * 32 + ke;
      GLD16(Ahi + ga, sb + tid * 8);
      GLD16(Alo + ga, sb + 4096 + tid * 8);
    }
    {
      int c = tid;
      int row = c >> 2;
      int pb  = (c & 3) << 4;
      int ke  = (pb ^ ((row & 3) << 4)) >> 1;
      size_t ga = (size_t)((row >> 6) * 512 + n0 + (row & 63)) * HD + kt * 32 + ke;
      GLD16(Bhi + ga, sb + 8192 + c * 8);
      GLD16(Blo + ga, sb + 14336 + c * 8);
      if (tid < 256){
        c = tid + 512;
        row = c >> 2;
        pb  = (c & 3) << 4;
        ke  = (pb ^ ((row & 3) << 4)) >> 1;
        ga  = (size_t)((row >> 6) * 512 + n0 + (row & 63)) * HD + kt * 32 + ke;
        GLD16(Bhi + ga, sb + 8192 + c * 8);
        GLD16(Blo + ga, sb + 14336 + c * 8);
      }
    }
  };

  stage(0, 0);
  for (int kt = 0; kt < 16; kt++){
    const int cur = kt & 1;
    __syncthreads();                       // waits vmcnt(0): tile `cur` resident
    if (kt + 1 < 16) stage(kt + 1, cur ^ 1);
    const unsigned short* sb = smem + cur * 20480;
    bf16x8 ah[4], al[4];
    #pragma unroll
    for (int mi = 0; mi < 4; mi++){
      int row = wm * 64 + mi * 16 + lr;
      int o = row * 32 + ((lkb ^ ((row & 3) << 4)) >> 1);
      ah[mi] = *(const bf16x8*)(sb + o);
      al[mi] = *(const bf16x8*)(sb + 4096 + o);
    }
    #pragma unroll
    for (int g = 0; g < 3; g++){
      int row = g * 64 + wn * 16 + lr;
      int o = row * 32 + ((lkb ^ ((row & 3) << 4)) >> 1);
      bf16x8 bh = *(const bf16x8*)(sb + 8192 + o);
      bf16x8 bl = *(const bf16x8*)(sb + 14336 + o);
      #pragma unroll
      for (int mi = 0; mi < 4; mi++){
        acc[g][mi] = __builtin_amdgcn_mfma_f32_16x16x32_bf16(ah[mi], bh, acc[g][mi], 0, 0, 0);
        acc[g][mi] = __builtin_amdgcn_mfma_f32_16x16x32_bf16(al[mi], bh, acc[g][mi], 0, 0, 0);
        acc[g][mi] = __builtin_amdgcn_mfma_f32_16x16x32_bf16(ah[mi], bl, acc[g][mi], 0, 0, 0);
      }
    }
  }

  // ----- fused GRU epilogue -----
  const float pe0 = pe[step * 4 + 0], pe1 = pe[step * 4 + 1],
              pe2 = pe[step * 4 + 2], pe3 = pe[step * 4 + 3];
  const int jg = n0 + wn * 16 + lr;
  const float* wrp = W_ih + (size_t)jg * 8;
  const float* wzp = W_ih + (size_t)(512 + jg) * 8;
  const float* wnp = W_ih + (size_t)(1024 + jg) * 8;
  float4 wr0 = *(const float4*)wrp, wr1 = *(const float4*)(wrp + 4);
  float4 wz0 = *(const float4*)wzp, wz1 = *(const float4*)(wzp + 4);
  float4 wn0 = *(const float4*)wnp, wn1 = *(const float4*)(wnp + 4);
  float cr = pe0*wr1.x + pe1*wr1.y + pe2*wr1.z + pe3*wr1.w + b_ih[jg]       + b_hh[jg];
  float cz = pe0*wz1.x + pe1*wz1.y + pe2*wz1.z + pe3*wz1.w + b_ih[512+jg]   + b_hh[512+jg];
  float cn = pe0*wn1.x + pe1*wn1.y + pe2*wn1.z + pe3*wn1.w + b_ih[1024+jg];
  const float bhn = b_hh[1024 + jg];

  #pragma unroll
  for (int mi = 0; mi < 4; mi++){
    #pragma unroll
    for (int q = 0; q < 4; q++){
      int brow = wm * 64 + mi * 16 + ((l >> 4) << 2) + q;
      size_t bg = (size_t)(b0 + brow);
      float4 x = *(const float4*)(last_ws + bg * 4);
      float gr = x.x*wr0.x + x.y*wr0.y + x.z*wr0.z + x.w*wr0.w + cr + acc[0][mi][q];
      float gz = x.x*wz0.x + x.y*wz0.y + x.z*wz0.z + x.w*wz0.w + cz + acc[1][mi][q];
      float gn = x.x*wn0.x + x.y*wn0.y + x.z*wn0.z + x.w*wn0.w + cn;
      float r = 1.f / (1.f + exp2f(-1.44269504f * gr));
      float z = 1.f / (1.f + exp2f(-1.44269504f * gz));
      float nn = gn + r * (acc[2][mi][q] + bhn);
      float th = 1.f - 2.f / (1.f + exp2f(2.88539008f * nn));
      size_t hoff = bg * HD + jg;
      float h = bf2f(Ahi[hoff]) + bf2f(Alo[hoff]);   // reconstruct h2 (err ~2e-5)
      hidden[hoff] = (1.f - z) * th + z * h;
    }
  }
}

// ------- last step's output column -------
__global__ __launch_bounds__(256) void final_out(
    const float* __restrict__ hidden, const float* __restrict__ Wlin,
    const float* __restrict__ ctxdot, float* __restrict__ outp)
{
  int tid = threadIdx.x; int l = tid & 63; int w = tid >> 6;
  int b = blockIdx.x * 4 + w;
  const float* hb = hidden + (size_t)b * HD;
  float p = 0.f;
  #pragma unroll
  for (int j = 0; j < 8; j++) p += hb[l + 64 * j] * Wlin[l + 64 * j];
  p = wsum(p);
  if (l == 0) outp[(size_t)b * T_OUT + 11] = p + ctxdot[b];
}

extern "C" void kernel_launch(void* const* d_in, const int* in_sizes, int n_in,
                              void* d_out, int out_size, void* d_ws, size_t ws_size,
                              hipStream_t stream){
  (void)in_sizes; (void)n_in; (void)out_size; (void)ws_size;
  const float* enc   = (const float*)d_in[0];
  const float* ehid  = (const float*)d_in[1];
  const float* last0 = (const float*)d_in[2];
  const float* pe    = (const float*)d_in[3];
  const float* W_ih  = (const float*)d_in[4];
  const float* W_hh  = (const float*)d_in[5];
  const float* b_ih  = (const float*)d_in[6];
  const float* b_hh  = (const float*)d_in[7];
  const float* W_lin = (const float*)d_in[8];
  const float* b_lin = (const float*)d_in[9];
  float* outp = (float*)d_out;

  char* ws = (char*)d_ws;
  size_t off = 0;
  auto alloc = [&](size_t bytes){ void* p = ws + off; off += (bytes + 255) & ~(size_t)255; return p; };
  unsigned short* whh_hi = (unsigned short*)alloc((size_t)1536 * 512 * 2);
  unsigned short* whh_lo = (unsigned short*)alloc((size_t)1536 * 512 * 2);
  unsigned short* h2hi   = (unsigned short*)alloc((size_t)NB * HD * 2);
  unsigned short* h2lo   = (unsigned short*)alloc((size_t)NB * HD * 2);
  float*          hidden = (float*)         alloc((size_t)NB * HD * 4);
  float*          lastw  = (float*)         alloc((size_t)NB * 4 * 4);
  float*          ctxd   = (float*)         alloc((size_t)NB * 4);

  conv_whh<<<3072, 256, 0, stream>>>(W_hh, whh_hi, whh_lo);
  for (int s = 0; s < T_OUT; s++){
    // rev = s&1: alternate-direction batch walk -> Infinity-Cache retention of
    // the enc tail read last by the previous step (256MB L3 vs 403MB stream)
    attn_step<<<NB, 256, 0, stream>>>(enc, s == 0 ? ehid : hidden, W_lin, b_lin,
                                      last0, lastw, ctxd, h2hi, h2lo, outp, s, s & 1);
    gru_gemm<<<512, 512, 0, stream>>>(h2hi, h2lo, whh_hi, whh_lo,
                                      lastw, pe, W_ih, b_ih, b_hh, hidden, s);
  }
  final_out<<<2048, 256, 0, stream>>>(hidden, W_lin, ctxd, outp);
}